// Round 1
// 251.710 us; speedup vs baseline: 1.0070x; 1.0070x over previous
//
#include <hip/hip_runtime.h>

// Batched Kalman predict: x_hat = Ap x ; P_hat = Ap P Ap^T + Q
// 8 threads per element, one P-row per thread -> every global access from a
// wave covers a contiguous 2KB span (full cache-line utilization, write merge).
// Cross-row mixing (left-multiply by Ap) staged through LDS, *within one wave*
// (8-lane groups), so no block barrier is needed.
//
// Ap = triu(relu(A)) and the per-row sigma table are computed ONCE by a 1-wave
// setup kernel into a __device__ constant block; the main kernel reads them as
// uniform (scalar-load-eligible) values. Previously every one of 62.5k waves
// recomputed relu/triu/readfirstlane (~100+ VALU/lane) for a constant 8x8.
//
// LDS layout: element stride 100 dwords (== 4 mod 32), row stride 12 dwords.
// Read instruction (fixed j): bank starts = (4*d + 12*j) mod 32, d=0..7 within
// a wave -> 8 distinct starts, all 32 banks, conflict-free b128.

#define ROW_STRIDE 12
#define ELEM_STRIDE 100
#define ELEMS_PER_BLOCK 32   // 256 threads / 8 rows

// g_cst[0..63]  : Ap = triu(relu(A)), row-major, zeros included
// g_cst[64..71] : per-row sigma  (sp,sp,sp,sp, sv,sv,sv,sv)
__device__ __align__(16) float g_cst[72];

__global__ void kalman_setup_kernel(const float* __restrict__ A,
                                    const float* __restrict__ sigp_ptr,
                                    const float* __restrict__ sigv_ptr)
{
    int t = threadIdx.x;
    if (t < 64) {
        float a = fmaxf(A[t], 0.0f);            // relu
        if ((t & 7) < (t >> 3)) a = 0.0f;       // triu
        g_cst[t] = a;
    }
    if (t < 8) g_cst[64 + t] = (t < 4) ? sigp_ptr[0] : sigv_ptr[0];
}

__global__ __launch_bounds__(256) void kalman_predict_kernel(
    const float* __restrict__ x,
    const float* __restrict__ P,
    float* __restrict__ x_hat,
    float* __restrict__ P_hat,
    int B)
{
    __shared__ float lds_m[ELEMS_PER_BLOCK * ELEM_STRIDE];

    int tid = blockIdx.x * blockDim.x + threadIdx.x;
    int e = tid >> 3;           // batch element
    int r = tid & 7;            // row within element
    int e_l = threadIdx.x >> 3; // element slot within block (0..31)

    bool valid = (e < B);
    int e_c = valid ? e : (B - 1);   // clamp loads; stores predicated

    // ---- own P row (32B, wave covers contiguous 2KB via 2 insts) ----
    unsigned poff = (unsigned)e_c * 64u + (unsigned)r * 8u;
    const float4* prow = (const float4*)(P + poff);
    float4 pa = prow[0], pb = prow[1];
    float p[8] = {pa.x, pa.y, pa.z, pa.w, pb.x, pb.y, pb.z, pb.w};

    // ---- own x (all 8 values; 8 lanes share the same 32B -> L1 broadcast) ----
    const float4* xrow = (const float4*)(x + (unsigned)e_c * 8u);
    float4 x0 = xrow[0], x1 = xrow[1];
    float xv[8] = {x0.x, x0.y, x0.z, x0.w, x1.x, x1.y, x1.z, x1.w};

    // ---- uniform Ap (pre-masked; uniform addr + restrict stores -> s_load) ----
    float ap[64];
#pragma unroll
    for (int t = 0; t < 64; ++t) ap[t] = g_cst[t];

    // ---- per-lane Ap row r (runtime r -> divergent vector load, L1-hot) ----
    const float4* arow = (const float4*)(g_cst + r * 8);
    float4 a0 = arow[0], a1 = arow[1];
    float apr[8] = {a0.x, a0.y, a0.z, a0.w, a1.x, a1.y, a1.z, a1.w};

    float sig = g_cst[64 + r];

    // ---- step 1: M row r = P row r * Ap^T ----
    // Ap is upper-triangular: ap[l][k] == 0 for k < l -> 36 FMAs, not 64.
    float m[8];
#pragma unroll
    for (int l = 0; l < 8; ++l) {
        float s = 0.0f;
#pragma unroll
        for (int k = l; k < 8; ++k) s = fmaf(ap[l * 8 + k], p[k], s);
        m[l] = s;
    }

    // ---- stage M row in LDS (consumed only by this wave's own 8-lane group) ----
    float* slot = lds_m + e_l * ELEM_STRIDE + r * ROW_STRIDE;
    ((float4*)slot)[0] = make_float4(m[0], m[1], m[2], m[3]);
    ((float4*)(slot + 4))[0] = make_float4(m[4], m[5], m[6], m[7]);

    // Intra-wave visibility only: mixing reads slots written by lanes of the
    // SAME wave. Wait for our ds_writes; no block barrier (waves decoupled).
    asm volatile("s_waitcnt lgkmcnt(0)" ::: "memory");

    // ---- Q diag entry for row r ----
    float hv = (r & 1) ? xv[3] : xv[2];
    float q = hv * sig;
    q = q * q;

    // ---- x_hat row r ----
    float xh = 0.0f;
#pragma unroll
    for (int j = 0; j < 8; ++j) xh = fmaf(apr[j], xv[j], xh);

    // ---- step 2: out[l] = sum_j apr[j] * M[j][l] + (l==r)*q ----
    // apr[j] == 0 for j < r (pre-masked), so extra FMAs are harmless.
    float out[8];
#pragma unroll
    for (int l = 0; l < 8; ++l) out[l] = (l == r) ? q : 0.0f;

    const float* ebase = lds_m + e_l * ELEM_STRIDE;
#pragma unroll
    for (int j = 0; j < 8; ++j) {
        const float4* mr = (const float4*)(ebase + j * ROW_STRIDE);
        float4 ma = mr[0], mb = mr[1];
        float mj[8] = {ma.x, ma.y, ma.z, ma.w, mb.x, mb.y, mb.z, mb.w};
#pragma unroll
        for (int l = 0; l < 8; ++l) out[l] = fmaf(apr[j], mj[l], out[l]);
    }

    // ---- stores: x_hat 4B/lane contiguous; P_hat rows cover contiguous 2KB ----
    if (valid) {
        x_hat[(unsigned)e * 8u + r] = xh;
        float4* po = (float4*)(P_hat + poff);
        po[0] = make_float4(out[0], out[1], out[2], out[3]);
        po[1] = make_float4(out[4], out[5], out[6], out[7]);
    }
}

extern "C" void kernel_launch(void* const* d_in, const int* in_sizes, int n_in,
                              void* d_out, int out_size, void* d_ws, size_t ws_size,
                              hipStream_t stream) {
    const float* x  = (const float*)d_in[0];
    const float* P  = (const float*)d_in[1];
    const float* A  = (const float*)d_in[2];
    const float* sp = (const float*)d_in[3];
    const float* sv = (const float*)d_in[4];

    int B = in_sizes[0] / 8;           // x is (B, 8, 1)
    float* x_hat = (float*)d_out;      // B*8 floats
    float* P_hat = (float*)d_out + (size_t)B * 8;  // B*64 floats

    kalman_setup_kernel<<<1, 64, 0, stream>>>(A, sp, sv);

    int threads = B * 8;
    int block = 256;
    int grid = (threads + block - 1) / block;
    kalman_predict_kernel<<<grid, block, 0, stream>>>(x, P, x_hat, P_hat, B);
}